// Round 4
// baseline (206.294 us; speedup 1.0000x reference)
//
#include <hip/hip_runtime.h>
#include <math.h>

#define BATCH 64
#define LSEQ 2048
#define DMOD 256
#define KC 32
#define LCHUNK 128  // l's per block -> 1024 blocks, 4 resident/CU
#define LS 32       // l's per subtile
#define NSUB 4
#define PITCH_D 264 // bf16 pitch, d-fast tile (528B rows: 16B-aligned, even banks)
#define PITCH_T 36  // bf16 pitch, l-fast tiles (72B rows: 8B-aligned, 18-dw stride spreads banks)

typedef __bf16 bf16x8 __attribute__((ext_vector_type(8)));
typedef __bf16 bf16x4 __attribute__((ext_vector_type(4)));
typedef float f32x4 __attribute__((ext_vector_type(4)));

static __device__ __forceinline__ bf16x8 cat8(bf16x4 a, bf16x4 b) {
  return __builtin_shufflevector(a, b, 0, 1, 2, 3, 4, 5, 6, 7);
}

// One block: (b, 128-l chunk). C_u[32 k][256 d] = sum_l exp(s[l,k])*rev[l,d],
// Z[32 k] = sum_l exp(s[l,k]). No max subtraction (|s| <~ 7, exp<=1100 safe).
// LDS ~37.9 KB -> 4 blocks/CU; W held in VGPRs (no sW).
__global__ __launch_bounds__(256, 4) void fused_pool_kernel(
    const float* __restrict__ rev, const float* __restrict__ W,
    float* __restrict__ cPartial, float* __restrict__ zPartial) {
  __shared__ __align__(16) __bf16 sRev[LS * PITCH_D];    // rev[l][d], d-fast (GEMM1 A)
  __shared__ __align__(16) __bf16 sRevT[DMOD * PITCH_T]; // rev[d][l], l-fast (GEMM2 B)
  __shared__ __align__(16) __bf16 sP[KC * PITCH_T];      // p[k][l],  l-fast (GEMM2 A)
  __shared__ float sZw[4][16];

  const int tid = threadIdx.x;
  const int b = blockIdx.y;
  const int lc = blockIdx.x;
  const int lbase = lc * LCHUNK;
  const int lane = tid & 63;
  const int wave = tid >> 6;
  const int col = lane & 15;
  const int quad = lane >> 4;

  const int Mt = wave & 1;   // GEMM1: l-half; GEMM2: k-half
  const int Nt = wave >> 1;  // GEMM1: k-half; GEMM2: d-half group

  // ---- W B-frags -> registers, once per block ----
  // B[kd=d][n=kcode]: lane n = Nt*16+col, kd = ks*32 + quad*8 + j
  bf16x8 wfrag[8];
  {
    const float* wrow = W + (Nt * 16 + col) * DMOD + quad * 8;
#pragma unroll
    for (int ks = 0; ks < 8; ++ks) {
      float4 a = *(const float4*)(wrow + ks * 32);
      float4 c = *(const float4*)(wrow + ks * 32 + 4);
      bf16x4 lo = {(__bf16)a.x, (__bf16)a.y, (__bf16)a.z, (__bf16)a.w};
      bf16x4 hi = {(__bf16)c.x, (__bf16)c.y, (__bf16)c.z, (__bf16)c.w};
      wfrag[ks] = cat8(lo, hi);
    }
  }

  f32x4 acc2[8];
#pragma unroll
  for (int i = 0; i < 8; ++i) acc2[i] = (f32x4){0.f, 0.f, 0.f, 0.f};
  float zl = 0.f;  // z partial for k = Nt*16+col over this wave's l's

  for (int sub = 0; sub < NSUB; ++sub) {
    const int l0 = lbase + sub * LS;
    __syncthreads();  // A: previous sub's GEMMs done before overwrite

    // ---- stage rev 32x256 fp32 -> bf16 sRev (coalesced float4) ----
#pragma unroll
    for (int i = 0; i < 8; ++i) {
      int slot = tid + 256 * i;
      int r = slot >> 6, c4 = slot & 63;
      float4 v = *(const float4*)(rev + ((size_t)b * LSEQ + l0 + r) * DMOD + c4 * 4);
      bf16x4 h = {(__bf16)v.x, (__bf16)v.y, (__bf16)v.z, (__bf16)v.w};
      *(bf16x4*)(&sRev[r * PITCH_D + c4 * 4]) = h;
    }
    __syncthreads();  // B: sRev visible

    // ---- transpose sRev[l][d] -> sRevT[d][l] (tid = d) ----
#pragma unroll
    for (int j4 = 0; j4 < 4; ++j4) {
      bf16x4 lo, hi;
#pragma unroll
      for (int j = 0; j < 4; ++j) lo[j] = sRev[(j4 * 8 + j) * PITCH_D + tid];
#pragma unroll
      for (int j = 0; j < 4; ++j) hi[j] = sRev[(j4 * 8 + 4 + j) * PITCH_D + tid];
      *(bf16x4*)(&sRevT[tid * PITCH_T + j4 * 8]) = lo;
      *(bf16x4*)(&sRevT[tid * PITCH_T + j4 * 8 + 4]) = hi;
    }

    // ---- GEMM1: C1[l][k] tile (Mt l-half x Nt k-half), K=256 ----
    f32x4 acc1 = {0.f, 0.f, 0.f, 0.f};
#pragma unroll
    for (int ks = 0; ks < 8; ++ks) {
      bf16x8 af = *(const bf16x8*)(&sRev[(Mt * 16 + col) * PITCH_D + ks * 32 + quad * 8]);
      acc1 = __builtin_amdgcn_mfma_f32_16x16x32_bf16(af, wfrag[ks], acc1, 0, 0, 0);
    }
    // C1: row(m=l)=quad*4+reg, col(n=k)=lane&15. exp -> sP[k][l] (l-fast)
#pragma unroll
    for (int reg = 0; reg < 4; ++reg) {
      float p = __expf(acc1[reg]);
      __bf16 ph = (__bf16)p;
      zl += (float)ph;
      sP[(Nt * 16 + col) * PITCH_T + Mt * 16 + quad * 4 + reg] = ph;
    }
    __syncthreads();  // C: sP + sRevT visible

    // ---- GEMM2: C2[k][d] (Mt k-half x Nt d-128), K=32 (one step) ----
    // A2[m=k][kd=l] from sP; B2[kd=l][n=d] from sRevT (b64 pairs, 72B rows)
    bf16x4 pa0 = *(const bf16x4*)(&sP[(Mt * 16 + col) * PITCH_T + quad * 8]);
    bf16x4 pa1 = *(const bf16x4*)(&sP[(Mt * 16 + col) * PITCH_T + quad * 8 + 4]);
    bf16x8 pa = cat8(pa0, pa1);
#pragma unroll
    for (int nt = 0; nt < 8; ++nt) {
      int drow = (Nt * 8 + nt) * 16 + col;
      bf16x4 b0 = *(const bf16x4*)(&sRevT[drow * PITCH_T + quad * 8]);
      bf16x4 b1 = *(const bf16x4*)(&sRevT[drow * PITCH_T + quad * 8 + 4]);
      acc2[nt] = __builtin_amdgcn_mfma_f32_16x16x32_bf16(pa, cat8(b0, b1), acc2[nt], 0, 0, 0);
    }
  }

  // ---- Z: zl holds z[k=Nt*16+col] over l in {Mt*16+quad*4+0..3, all subs} ----
  zl += __shfl_xor(zl, 16, 64);
  zl += __shfl_xor(zl, 32, 64);
  if (quad == 0) sZw[wave][col] = zl;
  __syncthreads();
  if (tid < KC) {
    int Ntt = tid >> 4, c = tid & 15;
    zPartial[((size_t)b * 16 + lc) * KC + tid] = sZw[2 * Ntt][c] + sZw[2 * Ntt + 1][c];
  }

  // ---- store C2 partial: row(m=k)=Mt*16+quad*4+reg, col(n=d) ----
  float* dst = cPartial + (((size_t)b * 16 + lc) * KC) * DMOD;
#pragma unroll
  for (int nt = 0; nt < 8; ++nt) {
    int d = (Nt * 8 + nt) * 16 + col;
#pragma unroll
    for (int reg = 0; reg < 4; ++reg) {
      int k = Mt * 16 + quad * 4 + reg;
      dst[k * DMOD + d] = acc2[nt][reg];
    }
  }
}

// out[b][k][d] = (sum_lc C_u) / (sum_lc Z), float4-vectorized
__global__ __launch_bounds__(256) void reduce_kernel(
    const float* __restrict__ cPartial, const float* __restrict__ zPartial,
    float* __restrict__ out) {
  int idx = blockIdx.x * 256 + threadIdx.x;  // 131072 float4 slots
  int b = idx >> 11;
  int k = (idx >> 6) & 31;
  float4 s = {0.f, 0.f, 0.f, 0.f};
  float z = 0.f;
#pragma unroll
  for (int lcc = 0; lcc < 16; ++lcc) {
    const float4 v = *(const float4*)(cPartial +
                                      ((((size_t)b * 16 + lcc) * KC + k) << 8) +
                                      ((idx & 63) << 2));
    s.x += v.x; s.y += v.y; s.z += v.z; s.w += v.w;
    z += zPartial[((size_t)b * 16 + lcc) * KC + k];
  }
  float zi = 1.0f / z;
  float4 o = {s.x * zi, s.y * zi, s.z * zi, s.w * zi};
  *(float4*)(out + ((size_t)idx << 2)) = o;
}

extern "C" void kernel_launch(void* const* d_in, const int* in_sizes, int n_in,
                              void* d_out, int out_size, void* d_ws,
                              size_t ws_size, hipStream_t stream) {
  const float* rev = (const float*)d_in[0];  // 64*2048*256 fp32
  const float* W = (const float*)d_in[1];    // 32*256 fp32
  float* out = (float*)d_out;                // 64*32*256 fp32

  float* ws = (float*)d_ws;
  float* cPartial = ws;                                         // 64*16*32*256 floats
  float* zPartial = cPartial + (size_t)BATCH * 16 * KC * DMOD;  // 64*16*32 floats

  fused_pool_kernel<<<dim3(16, BATCH), dim3(256), 0, stream>>>(rev, W, cPartial,
                                                               zPartial);
  reduce_kernel<<<dim3(512), dim3(256), 0, stream>>>(cPartial, zPartial, out);
}